// Round 18
// baseline (545.493 us; speedup 1.0000x reference)
//
#include <hip/hip_runtime.h>
#include <hip/hip_bf16.h>

#define EE 256
#define HIDD 150
#define HP 160
#define NN 384
#define NB 2
#define NJT 6
#define RPB 4
#define NTASK 18432  // 2304 (b,i-pair,jt) units x 4 wp x 2 jf  (16-j subtile tasks)
#define NWORK 2048   // 256 blocks x 8 waves -> exactly 9 tasks per wave

typedef float f32x4 __attribute__((ext_vector_type(4)));
typedef _Float16 half8 __attribute__((ext_vector_type(8)));
typedef _Float16 half4 __attribute__((ext_vector_type(4)));

__device__ __forceinline__ void gload16(const _Float16* g, _Float16* l) {
  __builtin_amdgcn_global_load_lds(
      (const __attribute__((address_space(1))) unsigned int*)g,
      (__attribute__((address_space(3))) unsigned int*)l, 16, 0, 0);
}

// ---- merged prep: blocks 0..259 pack weights; blocks 260..451 compute U/V/Xh ----
// frag k-convention: index=lane&15, k=(lane>>4)*8+e (within each 32-K step)
// w1p (40960 halfs) and w2p (25600 halfs) are CONTIGUOUS in d_ws -> one 133KB blob.
__global__ void prep(const float* __restrict__ W1, const float* __restrict__ W2,
                     const float* __restrict__ b2, const float* __restrict__ X,
                     const float* __restrict__ b1,
                     _Float16* __restrict__ w1p, _Float16* __restrict__ w2p,
                     _Float16* __restrict__ Xh, float* __restrict__ U,
                     float* __restrict__ V) {
  __shared__ float xs[RPB][EE];
  int blk = blockIdx.x;
  int tid = threadIdx.x;
  if (blk < 260) {
    int idx = blk * 256 + tid;
    if (idx < 40960) {
      int e = idx & 7, lane = (idx >> 3) & 63, tile = idx >> 9;
      int t = tile % 10, k8 = tile / 10;
      int eg = k8 * 32 + ((lane >> 4) << 3) + e;
      int h = t * 16 + (lane & 15);
      w1p[idx] = (_Float16)((h < HIDD) ? W1[(512 + eg) * HIDD + h] : 0.f);
    }
    int idx2 = idx - 40960;
    if (idx2 >= 0 && idx2 < 25600) {
      int e = idx2 & 7, lane = (idx2 >> 3) & 63, tile = idx2 >> 9;
      int t = tile % 10, k5 = tile / 10;
      int kk = k5 * 32 + ((lane >> 4) << 3) + e;
      int h = t * 16 + (lane & 15);
      float v = 0.f;
      if (h < HIDD) {
        if (kk < HIDD) v = W2[kk * HIDD + h];
        else if (kk == HIDD) v = b2[h];  // b2 folded: h1[.][150] forced to 1.0 in main
      }
      w2p[idx2] = (_Float16)v;
    }
  } else {
    int r0 = (blk - 260) * RPB;
    for (int q = tid; q < RPB * EE; q += 256) {
      float xv = X[r0 * EE + q];
      xs[q >> 8][q & 255] = xv;
      Xh[r0 * EE + q] = (_Float16)xv;
    }
    __syncthreads();
    int h = tid;
    if (h < HP) {
      float u[RPB] = {0, 0, 0, 0}, v[RPB] = {0, 0, 0, 0};
      if (h < HIDD) {
        for (int e = 0; e < EE; e++) {
          float wa = W1[e * HIDD + h];
          float wb = W1[(EE + e) * HIDD + h];
          #pragma unroll
          for (int r = 0; r < RPB; r++) {
            u[r] = fmaf(xs[r][e], wa, u[r]);
            v[r] = fmaf(xs[r][e], wb, v[r]);
          }
        }
        float bb = b1[h];
        #pragma unroll
        for (int r = 0; r < RPB; r++) u[r] += bb;
      }
      #pragma unroll
      for (int r = 0; r < RPB; r++) {
        U[(r0 + r) * HP + h] = u[r];
        V[(r0 + r) * HP + h] = v[r];
      }
    }
  }
}

// ---- main: PERSISTENT weights-in-LDS. Grid = 256 blocks x 8 waves. Stage ALL
// packed weights (133 KB) once + ONE barrier; each wave runs EXACTLY 9 fine
// tasks (1 i x 16 j), zero barriers -> perfect balance, single code body with
// ~60% of r11's peak live registers. B-frags via ds_read_b128; h1 in regs via
// ds_bpermute (proven numerics of r17's tail block).
__global__ __launch_bounds__(512, 2) void pair_main(
    const _Float16* __restrict__ Xh, const float* __restrict__ M,
    const float* __restrict__ W3, const float* __restrict__ b3,
    const float* __restrict__ U, const float* __restrict__ V,
    const _Float16* __restrict__ w1p, const _Float16* __restrict__ w2p,
    float* __restrict__ out) {
  int tid = threadIdx.x;
  int lane = tid & 63;
  int w = tid >> 6;        // 0..7
  int hcol = lane & 15;
  int rgrp = lane >> 4;

  __shared__ __align__(16) _Float16 wbuf[66560];  // w1p(40960) ++ w2p(25600) = 133 KB
  __shared__ float W3s[HP];

  // ---- stage all weights: 130 x 1KB wave-ops ----
  #pragma unroll
  for (int s = 0; s < 16; s++) {
    int off = (s * 8 + w) * 512;
    gload16(w1p + off + lane * 8, &wbuf[off]);
  }
  if (w < 2) {
    int off = (128 + w) * 512;
    gload16(w1p + off + lane * 8, &wbuf[off]);
  }
  if (tid < HP) W3s[tid] = (tid < HIDD) ? W3[tid] : 0.f;
  __syncthreads();  // the ONLY barrier

  float bb3 = b3[0];
  int la = (hcol + ((rgrp & 1) << 5)) << 2;  // bpermute src lane A (byte addr)
  int lb = la + 64;                          // src lane B = A + 16 lanes
  bool losel = (rgrp < 2);
  int ws = (blockIdx.x << 3) + w;            // wave slot 0..2047

  #pragma unroll 1
  for (int r = 0; r < 9; r++) {
    int tau = ws + r * NWORK;  // < 18432 always; exact balance
    // decode: bxp (b,i-pair,jt) | wp (i-low, j-half) | jf (16-j subtile)
    int bxp = tau >> 3;
    int rem = tau & 7;
    int wp = rem >> 1, jf = rem & 1;
    int jt = bxp % NJT;
    int ig = (bxp / NJT) % (NN / 2);
    int b = bxp / (NJT * (NN / 2));
    int il = wp >> 1, jh = wp & 1;
    int i = ig * 2 + il;
    int j0 = jt * 64 + jh * 32 + jf * 16;    // base of this task's 16 j-rows

    const _Float16* xi = Xh + (size_t)(b * NN + i) * EE;
    const _Float16* xr = Xh + (size_t)(b * NN + j0 + hcol) * EE;

    // acc = C1^T[h, j]; init U[i,h] + V[j,h]  (direct L2 float4 loads)
    f32x4 acc[10];
    #pragma unroll
    for (int t = 0; t < 10; t++) {
      int h0 = t * 16 + rgrp * 4;
      float4 u4 = *reinterpret_cast<const float4*>(U + (size_t)(b * NN + i) * HP + h0);
      float4 v4 = *reinterpret_cast<const float4*>(
          V + (size_t)(b * NN + j0 + hcol) * HP + h0);
      acc[t][0] = u4.x + v4.x; acc[t][1] = u4.y + v4.y;
      acc[t][2] = u4.z + v4.z; acc[t][3] = u4.w + v4.w;
    }

    // ---- GEMM1: C1^T[h,j] += W1c^T (xi.xj), 8 K-steps, weights from LDS ----
    #pragma unroll
    for (int k8 = 0; k8 < 8; k8++) {
      half8 xi_s = *reinterpret_cast<const half8*>(xi + k8 * 32 + rgrp * 8);
      half8 xj = *reinterpret_cast<const half8*>(xr + k8 * 32 + rgrp * 8);
      half8 a0 = xi_s * xj;
      #pragma unroll
      for (int t = 0; t < 10; t++) {
        half8 bf = *reinterpret_cast<const half8*>(&wbuf[k8 * 5120 + t * 512 + lane * 8]);
        acc[t] = __builtin_amdgcn_mfma_f32_16x16x32_f16(bf, a0, acc[t], 0, 0, 0);
      }
    }

    // ---- relu -> fp16 h1 kept in registers as dword pairs ----
    int Hd[10][2];
    #pragma unroll
    for (int t = 0; t < 10; t++) {
      half4 hv;
      hv[0] = (_Float16)fmaxf(acc[t][0], 0.f);
      hv[1] = (_Float16)fmaxf(acc[t][1], 0.f);
      hv[2] = (_Float16)fmaxf(acc[t][2], 0.f);
      hv[3] = (_Float16)fmaxf(acc[t][3], 0.f);
      if (t == 9 && rgrp == 1) hv[2] = (_Float16)1.0f;  // h=150: b2 via W2 k-row
      int2 q = __builtin_bit_cast(int2, hv);
      Hd[t][0] = q.x;
      Hd[t][1] = q.y;
    }

    // ---- GEMM2: D2^T[h2,j] = W2^T x h1^T; B-frag via fixed bpermute ----
    f32x4 acc2[10];
    #pragma unroll
    for (int t = 0; t < 10; t++) {
      acc2[t][0] = 0.f; acc2[t][1] = 0.f; acc2[t][2] = 0.f; acc2[t][3] = 0.f;
    }
    #pragma unroll
    for (int k5 = 0; k5 < 5; k5++) {
      int d0A = __builtin_amdgcn_ds_bpermute(la, Hd[2 * k5][0]);
      int d0B = __builtin_amdgcn_ds_bpermute(la, Hd[2 * k5 + 1][0]);
      int d1A = __builtin_amdgcn_ds_bpermute(la, Hd[2 * k5][1]);
      int d1B = __builtin_amdgcn_ds_bpermute(la, Hd[2 * k5 + 1][1]);
      int d2A = __builtin_amdgcn_ds_bpermute(lb, Hd[2 * k5][0]);
      int d2B = __builtin_amdgcn_ds_bpermute(lb, Hd[2 * k5 + 1][0]);
      int d3A = __builtin_amdgcn_ds_bpermute(lb, Hd[2 * k5][1]);
      int d3B = __builtin_amdgcn_ds_bpermute(lb, Hd[2 * k5 + 1][1]);
      int4 q;
      q.x = losel ? d0A : d0B;
      q.y = losel ? d1A : d1B;
      q.z = losel ? d2A : d2B;
      q.w = losel ? d3A : d3B;
      half8 b2f = __builtin_bit_cast(half8, q);
      #pragma unroll
      for (int t = 0; t < 10; t++) {
        half8 bf = *reinterpret_cast<const half8*>(
            &wbuf[40960 + k5 * 5120 + t * 512 + lane * 8]);
        acc2[t] = __builtin_amdgcn_mfma_f32_16x16x32_f16(bf, b2f, acc2[t], 0, 0, 0);
      }
    }

    // ---- layer 3: s[j] = sum_h2 relu(D2^T[h2,j]) * W3[h2]; reduce across rgrp ----
    float mi = M[b * NN + i];
    float p = 0.f;
    #pragma unroll
    for (int t = 0; t < 10; t++) {
      float4 w34 = *reinterpret_cast<const float4*>(&W3s[t * 16 + rgrp * 4]);
      p = fmaf(fmaxf(acc2[t][0], 0.f), w34.x, p);
      p = fmaf(fmaxf(acc2[t][1], 0.f), w34.y, p);
      p = fmaf(fmaxf(acc2[t][2], 0.f), w34.z, p);
      p = fmaf(fmaxf(acc2[t][3], 0.f), w34.w, p);
    }
    p += __shfl_xor(p, 16);
    p += __shfl_xor(p, 32);
    if (lane < 16) {
      int j = j0 + lane;
      float mj = M[b * NN + j];
      out[(size_t)(b * NN + i) * NN + j] = (mi + mj + p + bb3) * (1.f / 3.f);
    }
  }
}

extern "C" void kernel_launch(void* const* d_in, const int* in_sizes, int n_in,
                              void* d_out, int out_size, void* d_ws, size_t ws_size,
                              hipStream_t stream) {
  const float* X  = (const float*)d_in[0];
  const float* M  = (const float*)d_in[1];
  const float* W1 = (const float*)d_in[2];
  const float* b1 = (const float*)d_in[3];
  const float* W2 = (const float*)d_in[4];
  const float* b2 = (const float*)d_in[5];
  const float* W3 = (const float*)d_in[6];
  const float* b3 = (const float*)d_in[7];
  float* out = (float*)d_out;

  float* U  = (float*)d_ws;                        // 768*160 f32
  float* V  = U + NB * NN * HP;                    // 768*160 f32
  _Float16* Xh  = (_Float16*)(V + NB * NN * HP);   // 768*256 f16
  _Float16* w1p = Xh + NB * NN * EE;               // 40960 f16  (contiguous with w2p)
  _Float16* w2p = w1p + 40960;                     // 25600 f16

  hipLaunchKernelGGL(prep, dim3(452), dim3(256), 0, stream,
                     W1, W2, b2, X, b1, w1p, w2p, Xh, U, V);
  hipLaunchKernelGGL(pair_main, dim3(256), dim3(512), 0, stream,
                     Xh, M, W3, b3, U, V, w1p, w2p, out);
}

// Round 19
// 88.729 us; speedup vs baseline: 6.1479x; 6.1479x over previous
//
#include <hip/hip_runtime.h>
#include <hip/hip_bf16.h>

#define EE 256
#define HIDD 150
#define HP 160
#define NN 384
#define NB 2
#define NJT 6
#define RPB 4
#define NTASK 9216   // 2304 (b,i-pair,jt) units x 4 wave-tasks
#define NWORK 2048   // 256 blocks x 8 waves

typedef float f32x4 __attribute__((ext_vector_type(4)));
typedef _Float16 half8 __attribute__((ext_vector_type(8)));
typedef _Float16 half4 __attribute__((ext_vector_type(4)));

__device__ __forceinline__ void gload16(const _Float16* g, _Float16* l) {
  __builtin_amdgcn_global_load_lds(
      (const __attribute__((address_space(1))) unsigned int*)g,
      (__attribute__((address_space(3))) unsigned int*)l, 16, 0, 0);
}

// ---- merged prep: blocks 0..259 pack weights; blocks 260..451 compute U/V/Xh ----
// frag k-convention: index=lane&15, k=(lane>>4)*8+e (within each 32-K step)
// w1p (40960 halfs) and w2p (25600 halfs) are CONTIGUOUS in d_ws -> one 133KB blob.
__global__ void prep(const float* __restrict__ W1, const float* __restrict__ W2,
                     const float* __restrict__ b2, const float* __restrict__ X,
                     const float* __restrict__ b1,
                     _Float16* __restrict__ w1p, _Float16* __restrict__ w2p,
                     _Float16* __restrict__ Xh, float* __restrict__ U,
                     float* __restrict__ V) {
  __shared__ float xs[RPB][EE];
  int blk = blockIdx.x;
  int tid = threadIdx.x;
  if (blk < 260) {
    int idx = blk * 256 + tid;
    if (idx < 40960) {
      int e = idx & 7, lane = (idx >> 3) & 63, tile = idx >> 9;
      int t = tile % 10, k8 = tile / 10;
      int eg = k8 * 32 + ((lane >> 4) << 3) + e;
      int h = t * 16 + (lane & 15);
      w1p[idx] = (_Float16)((h < HIDD) ? W1[(512 + eg) * HIDD + h] : 0.f);
    }
    int idx2 = idx - 40960;
    if (idx2 >= 0 && idx2 < 25600) {
      int e = idx2 & 7, lane = (idx2 >> 3) & 63, tile = idx2 >> 9;
      int t = tile % 10, k5 = tile / 10;
      int kk = k5 * 32 + ((lane >> 4) << 3) + e;
      int h = t * 16 + (lane & 15);
      float v = 0.f;
      if (h < HIDD) {
        if (kk < HIDD) v = W2[kk * HIDD + h];
        else if (kk == HIDD) v = b2[h];  // b2 folded: h1[.][150] forced to 1.0 in main
      }
      w2p[idx2] = (_Float16)v;
    }
  } else {
    int r0 = (blk - 260) * RPB;
    for (int q = tid; q < RPB * EE; q += 256) {
      float xv = X[r0 * EE + q];
      xs[q >> 8][q & 255] = xv;
      Xh[r0 * EE + q] = (_Float16)xv;
    }
    __syncthreads();
    int h = tid;
    if (h < HP) {
      float u[RPB] = {0, 0, 0, 0}, v[RPB] = {0, 0, 0, 0};
      if (h < HIDD) {
        for (int e = 0; e < EE; e++) {
          float wa = W1[e * HIDD + h];
          float wb = W1[(EE + e) * HIDD + h];
          #pragma unroll
          for (int r = 0; r < RPB; r++) {
            u[r] = fmaf(xs[r][e], wa, u[r]);
            v[r] = fmaf(xs[r][e], wb, v[r]);
          }
        }
        float bb = b1[h];
        #pragma unroll
        for (int r = 0; r < RPB; r++) u[r] += bb;
      }
      #pragma unroll
      for (int r = 0; r < RPB; r++) {
        U[(r0 + r) * HP + h] = u[r];
        V[(r0 + r) * HP + h] = v[r];
      }
    }
  }
}

// ---- main: PERSISTENT weights-in-LDS. Grid = 256 blocks x 8 waves (1 block/CU).
// Stage ALL packed weights (133 KB) to LDS once + ONE barrier; then each wave
// independently executes 4-5 wave-tasks (1 i x 32 j, full 3-layer pipeline) with
// ZERO barriers: B-frags via contiguous ds_read_b128, h1 in regs via ds_bpermute.
__global__ __launch_bounds__(512, 2) void pair_main(
    const _Float16* __restrict__ Xh, const float* __restrict__ M,
    const float* __restrict__ W3, const float* __restrict__ b3,
    const float* __restrict__ U, const float* __restrict__ V,
    const _Float16* __restrict__ w1p, const _Float16* __restrict__ w2p,
    float* __restrict__ out) {
  int tid = threadIdx.x;
  int lane = tid & 63;
  int w = tid >> 6;        // 0..7
  int hcol = lane & 15;
  int rgrp = lane >> 4;

  __shared__ __align__(16) _Float16 wbuf[66560];  // w1p(40960) ++ w2p(25600) = 133 KB
  __shared__ float W3s[HP];

  // ---- stage all weights: 130 x 1KB wave-ops (w1p/w2p contiguous in d_ws) ----
  #pragma unroll
  for (int s = 0; s < 16; s++) {
    int off = (s * 8 + w) * 512;
    gload16(w1p + off + lane * 8, &wbuf[off]);
  }
  if (w < 2) {
    int off = (128 + w) * 512;
    gload16(w1p + off + lane * 8, &wbuf[off]);
  }
  if (tid < HP) W3s[tid] = (tid < HIDD) ? W3[tid] : 0.f;
  __syncthreads();  // the ONLY barrier

  float bb3 = b3[0];
  int la = (hcol + ((rgrp & 1) << 5)) << 2;  // bpermute src lane A (byte addr)
  int lb = la + 64;                          // src lane B = A + 16 lanes
  bool losel = (rgrp < 2);

  #pragma unroll 1
  for (int r = 0; r < 5; r++) {
    int tau = (blockIdx.x << 3) + w + r * NWORK;
    if (tau >= NTASK) break;
    // decode task: replicate round-10 (block bxp, wave wp) mapping
    int bxp = tau >> 2, wp = tau & 3;
    int jt = bxp % NJT;
    int ig = (bxp / NJT) % (NN / 2);
    int b = bxp / (NJT * (NN / 2));
    int il = wp >> 1, jh = wp & 1;
    int i = ig * 2 + il;

    const _Float16* xi = Xh + (size_t)(b * NN + i) * EE;
    const _Float16* xr0 = Xh + (size_t)(b * NN + jt * 64 + jh * 32 + hcol) * EE;
    const _Float16* xr1 = xr0 + 16 * EE;

    // acc = C1^T[h, j]; init U[i,h] + V[j,h]  (direct L2 float4 loads)
    f32x4 acc[2][10];
    #pragma unroll
    for (int t = 0; t < 10; t++) {
      int h0 = t * 16 + rgrp * 4;
      float4 u4 = *reinterpret_cast<const float4*>(U + (size_t)(b * NN + i) * HP + h0);
      #pragma unroll
      for (int jf = 0; jf < 2; jf++) {
        int jr = b * NN + jt * 64 + jh * 32 + jf * 16 + hcol;
        float4 v4 = *reinterpret_cast<const float4*>(V + (size_t)jr * HP + h0);
        acc[jf][t][0] = u4.x + v4.x; acc[jf][t][1] = u4.y + v4.y;
        acc[jf][t][2] = u4.z + v4.z; acc[jf][t][3] = u4.w + v4.w;
      }
    }

    // ---- GEMM1: C1^T[h,j] += W1c^T (xi.xj), 8 K-steps, weights from LDS ----
    #pragma unroll
    for (int k8 = 0; k8 < 8; k8++) {
      half8 xi_s = *reinterpret_cast<const half8*>(xi + k8 * 32 + rgrp * 8);
      half8 xj0 = *reinterpret_cast<const half8*>(xr0 + k8 * 32 + rgrp * 8);
      half8 xj1 = *reinterpret_cast<const half8*>(xr1 + k8 * 32 + rgrp * 8);
      half8 a0 = xi_s * xj0;
      half8 a1 = xi_s * xj1;
      #pragma unroll
      for (int t = 0; t < 10; t++) {
        half8 bf = *reinterpret_cast<const half8*>(&wbuf[k8 * 5120 + t * 512 + lane * 8]);
        acc[0][t] = __builtin_amdgcn_mfma_f32_16x16x32_f16(bf, a0, acc[0][t], 0, 0, 0);
        acc[1][t] = __builtin_amdgcn_mfma_f32_16x16x32_f16(bf, a1, acc[1][t], 0, 0, 0);
      }
    }

    // ---- relu -> fp16 h1 kept in registers as dword pairs ----
    int Hd[2][10][2];
    #pragma unroll
    for (int jf = 0; jf < 2; jf++) {
      #pragma unroll
      for (int t = 0; t < 10; t++) {
        half4 hv;
        hv[0] = (_Float16)fmaxf(acc[jf][t][0], 0.f);
        hv[1] = (_Float16)fmaxf(acc[jf][t][1], 0.f);
        hv[2] = (_Float16)fmaxf(acc[jf][t][2], 0.f);
        hv[3] = (_Float16)fmaxf(acc[jf][t][3], 0.f);
        if (t == 9 && rgrp == 1) hv[2] = (_Float16)1.0f;  // h=150: b2 via W2 k-row
        int2 q = __builtin_bit_cast(int2, hv);
        Hd[jf][t][0] = q.x;
        Hd[jf][t][1] = q.y;
      }
    }

    // ---- GEMM2: D2^T[h2,j] = W2^T x h1^T; B-frag built by fixed bpermute ----
    f32x4 acc2[2][10];
    #pragma unroll
    for (int jf = 0; jf < 2; jf++)
      #pragma unroll
      for (int t = 0; t < 10; t++) {
        acc2[jf][t][0] = 0.f; acc2[jf][t][1] = 0.f;
        acc2[jf][t][2] = 0.f; acc2[jf][t][3] = 0.f;
      }
    #pragma unroll
    for (int k5 = 0; k5 < 5; k5++) {
      half8 b2f[2];
      #pragma unroll
      for (int jf = 0; jf < 2; jf++) {
        int d0A = __builtin_amdgcn_ds_bpermute(la, Hd[jf][2 * k5][0]);
        int d0B = __builtin_amdgcn_ds_bpermute(la, Hd[jf][2 * k5 + 1][0]);
        int d1A = __builtin_amdgcn_ds_bpermute(la, Hd[jf][2 * k5][1]);
        int d1B = __builtin_amdgcn_ds_bpermute(la, Hd[jf][2 * k5 + 1][1]);
        int d2A = __builtin_amdgcn_ds_bpermute(lb, Hd[jf][2 * k5][0]);
        int d2B = __builtin_amdgcn_ds_bpermute(lb, Hd[jf][2 * k5 + 1][0]);
        int d3A = __builtin_amdgcn_ds_bpermute(lb, Hd[jf][2 * k5][1]);
        int d3B = __builtin_amdgcn_ds_bpermute(lb, Hd[jf][2 * k5 + 1][1]);
        int4 q;
        q.x = losel ? d0A : d0B;
        q.y = losel ? d1A : d1B;
        q.z = losel ? d2A : d2B;
        q.w = losel ? d3A : d3B;
        b2f[jf] = __builtin_bit_cast(half8, q);
      }
      #pragma unroll
      for (int t = 0; t < 10; t++) {
        half8 bf = *reinterpret_cast<const half8*>(
            &wbuf[40960 + k5 * 5120 + t * 512 + lane * 8]);
        acc2[0][t] = __builtin_amdgcn_mfma_f32_16x16x32_f16(bf, b2f[0], acc2[0][t], 0, 0, 0);
        acc2[1][t] = __builtin_amdgcn_mfma_f32_16x16x32_f16(bf, b2f[1], acc2[1][t], 0, 0, 0);
      }
    }

    // ---- layer 3: s[j] = sum_h2 relu(D2^T[h2,j]) * W3[h2]; reduce across rgrp ----
    float mi = M[b * NN + i];
    #pragma unroll
    for (int jf = 0; jf < 2; jf++) {
      float p = 0.f;
      #pragma unroll
      for (int t = 0; t < 10; t++) {
        float4 w34 = *reinterpret_cast<const float4*>(&W3s[t * 16 + rgrp * 4]);
        p = fmaf(fmaxf(acc2[jf][t][0], 0.f), w34.x, p);
        p = fmaf(fmaxf(acc2[jf][t][1], 0.f), w34.y, p);
        p = fmaf(fmaxf(acc2[jf][t][2], 0.f), w34.z, p);
        p = fmaf(fmaxf(acc2[jf][t][3], 0.f), w34.w, p);
      }
      p += __shfl_xor(p, 16);
      p += __shfl_xor(p, 32);
      if (lane < 16) {
        int j = jh * 32 + jf * 16 + lane;
        float mj = M[b * NN + jt * 64 + j];
        out[(size_t)(b * NN + i) * NN + jt * 64 + j] =
            (mi + mj + p + bb3) * (1.f / 3.f);
      }
    }
  }
}

extern "C" void kernel_launch(void* const* d_in, const int* in_sizes, int n_in,
                              void* d_out, int out_size, void* d_ws, size_t ws_size,
                              hipStream_t stream) {
  const float* X  = (const float*)d_in[0];
  const float* M  = (const float*)d_in[1];
  const float* W1 = (const float*)d_in[2];
  const float* b1 = (const float*)d_in[3];
  const float* W2 = (const float*)d_in[4];
  const float* b2 = (const float*)d_in[5];
  const float* W3 = (const float*)d_in[6];
  const float* b3 = (const float*)d_in[7];
  float* out = (float*)d_out;

  float* U  = (float*)d_ws;                        // 768*160 f32
  float* V  = U + NB * NN * HP;                    // 768*160 f32
  _Float16* Xh  = (_Float16*)(V + NB * NN * HP);   // 768*256 f16
  _Float16* w1p = Xh + NB * NN * EE;               // 40960 f16  (contiguous with w2p)
  _Float16* w2p = w1p + 40960;                     // 25600 f16

  hipLaunchKernelGGL(prep, dim3(452), dim3(256), 0, stream,
                     W1, W2, b2, X, b1, w1p, w2p, Xh, U, V);
  hipLaunchKernelGGL(pair_main, dim3(256), dim3(512), 0, stream,
                     Xh, M, W3, b3, U, V, w1p, w2p, out);
}